// Round 7
// baseline (492.674 us; speedup 1.0000x reference)
//
#include <hip/hip_runtime.h>
#include <hip/hip_bf16.h>

// AdditiveAttention on MI355X (gfx950)
// B=64, S=2048, D=512, U=512. All inputs fp32; output fp32 (B,D).
//
// R9: register liberation + intra-block pipeline. Diagnosis: WRITE_SIZE 49MB
// (~45MB scratch spills) in R5/R8 -- __launch_bounds__(512,4) forces <=128
// regs/wave; acc=64 AGPR leaves 64 VGPR: epilogue spills AND no B-load
// hoisting (MfmaUtil pinned ~16%). Fix: launch_bounds(512) (no min-wave,
// 1 block/CU expected) + R4's proven K-chunked double-buffered A-stage
// (4 chunks of 128, 2x16KB LDS, issue-early/write-late) so intra-block
// overlap replaces the lost inter-block overlap. Structure otherwise = R8
// (split-softmax + partial-ctx fusion, prep_k, comb_k).

typedef __attribute__((ext_vector_type(8))) short bf16x8;
typedef __attribute__((ext_vector_type(4))) float f32x4;

#if __has_builtin(__builtin_amdgcn_exp2f)
__device__ __forceinline__ float fast_exp2(float x) { return __builtin_amdgcn_exp2f(x); }
#else
__device__ __forceinline__ float fast_exp2(float x) { return exp2f(x); }
#endif
#if __has_builtin(__builtin_amdgcn_rcpf)
__device__ __forceinline__ float fast_rcp(float x) { return __builtin_amdgcn_rcpf(x); }
#else
__device__ __forceinline__ float fast_rcp(float x) { return 1.0f / x; }
#endif

__device__ __forceinline__ unsigned short f2bf(float f) {
  unsigned int u = __float_as_uint(f);
  u += 0x7fffu + ((u >> 16) & 1u);
  return (unsigned short)(u >> 16);
}

// pack two fp32 -> one dword of 2 bf16 (lo = a, hi = b), RNE via HIP intrinsics
__device__ __forceinline__ unsigned int cvt_pk_bf16(float a, float b) {
  const __hip_bfloat16 lo = __float2bfloat16(a);
  const __hip_bfloat16 hi = __float2bfloat16(b);
  const unsigned short ul = *reinterpret_cast<const unsigned short*>(&lo);
  const unsigned short uh = *reinterpret_cast<const unsigned short*>(&hi);
  return (unsigned int)ul | ((unsigned int)uh << 16);
}

// ---------------- k1: fused prep = qk (blocks 0..127) + wt_k (128..255) -----
// qk: Q = query @ W1, 64x2 sub-blocks x 256 thr.
// wt: Wtf fragment-ordered bf16(W2^T):
// Wtf[((ntile*16+ks)*64 + quad*16 + l15)*8 + j] = bf16(W2[ks*32+quad*8+j][ntile*16+l15])
__global__ __launch_bounds__(256) void prep_k(
    const float* __restrict__ query, const float* __restrict__ W1,
    const float* __restrict__ W2, float* __restrict__ Q,
    unsigned short* __restrict__ Wtf) {
  __shared__ float qrow[512];
  const int t = threadIdx.x;
  if (blockIdx.x < 128) {
    const int b = blockIdx.x >> 1, half = blockIdx.x & 1;
    qrow[t] = query[b * 512 + t];
    qrow[t + 256] = query[b * 512 + t + 256];
    __syncthreads();
    const int u = half * 256 + t;
    float acc = 0.f;
#pragma unroll 8
    for (int k = 0; k < 512; ++k) acc += qrow[k] * W1[(size_t)k * 512 + u];
    Q[b * 512 + u] = acc;
  } else {
    const int gid = (blockIdx.x - 128) * 256 + t;  // 0..32767
    const int lane = gid & 63;
    const int g = gid >> 6;  // ntile*16 + ks
    const int ks = g & 15, ntile = g >> 4;
    const int l15 = lane & 15, quad = lane >> 4;
    const int n = ntile * 16 + l15;
    const int k0 = ks * 32 + quad * 8;
    unsigned int p[4];
#pragma unroll
    for (int jj = 0; jj < 4; ++jj) {
      const float a = W2[(size_t)(k0 + 2 * jj) * 512 + n];
      const float b = W2[(size_t)(k0 + 2 * jj + 1) * 512 + n];
      p[jj] = (unsigned int)f2bf(a) | ((unsigned int)f2bf(b) << 16);
    }
    *(uint4*)&Wtf[(size_t)gid * 8] = make_uint4(p[0], p[1], p[2], p[3]);
  }
}

// ---------------- k2: fused scores + split-softmax partial context ----------
// Block: 64 rows x full U=512, K=512. 8 waves; wave w owns n-tiles w*4..w*4+3.
// A staged per 128-k chunk as bf16, double-buffered (2x16KB), XOR-swizzled;
// next chunk's global loads issued BEFORE the current chunk's MFMAs.
// B fragments: contiguous 1KB wave loads from fragment-ordered Wtf (L2-res);
// with the freed register budget the compiler can hoist them across ksteps.
// Epilogue: tanh+V1 reduce -> 64 row scores -> local softmax (m_i, d_i) ->
// partial ctx column per thread (global fp32 re-read, L2-hot).
__global__ __launch_bounds__(512) void scorectx_k(
    const float* __restrict__ values, const unsigned short* __restrict__ Wtf,
    const float* __restrict__ Q, const float* __restrict__ V1,
    float* __restrict__ Pstat, float* __restrict__ Pctx) {
  __shared__ __align__(16) unsigned short Ab[2][64 * 128];  // 2 x 16KB
  __shared__ float sAcc[64];
  __shared__ float wLDS[64];

  const int t = threadIdx.x;
  const int lane = t & 63;
  const int w = t >> 6;        // wave 0..7
  const int quad = lane >> 4;  // 0..3
  const int l15 = lane & 15;
  const int blk = blockIdx.x;
  const int m0 = blk * 64;
  const int b = m0 >> 11;  // /2048

  if (t < 64) sAcc[t] = 0.0f;

  // Staging geometry: thread t owns row sm = t>>3, 16 floats at col sp*16
  // of the current 128-k chunk. Writes two 16B chunks (XOR-swizzled by m&7).
  const int sm = t >> 3;  // 0..63
  const int sp = t & 7;   // 0..7
  const int sk = sm & 7;  // write swizzle key
  const float* src = values + (size_t)(m0 + sm) * 512 + sp * 16;
  const int wo0 = sm * 128 + (((2 * sp) ^ sk) * 8);
  const int wo1 = sm * 128 + (((2 * sp + 1) ^ sk) * 8);

  // ---- prologue: stage chunk 0 into buf 0
  {
    const f32x4* s4 = (const f32x4*)src;
    const f32x4 r0 = s4[0], r1 = s4[1], r2 = s4[2], r3 = s4[3];
    const unsigned int p0 = cvt_pk_bf16(r0[0], r0[1]);
    const unsigned int p1 = cvt_pk_bf16(r0[2], r0[3]);
    const unsigned int p2 = cvt_pk_bf16(r1[0], r1[1]);
    const unsigned int p3 = cvt_pk_bf16(r1[2], r1[3]);
    const unsigned int p4 = cvt_pk_bf16(r2[0], r2[1]);
    const unsigned int p5 = cvt_pk_bf16(r2[2], r2[3]);
    const unsigned int p6 = cvt_pk_bf16(r3[0], r3[1]);
    const unsigned int p7 = cvt_pk_bf16(r3[2], r3[3]);
    *(uint4*)&Ab[0][wo0] = make_uint4(p0, p1, p2, p3);
    *(uint4*)&Ab[0][wo1] = make_uint4(p4, p5, p6, p7);
  }
  __syncthreads();

  f32x4 acc[4][4];
#pragma unroll
  for (int mt = 0; mt < 4; ++mt)
#pragma unroll
    for (int nt = 0; nt < 4; ++nt) acc[mt][nt] = (f32x4){0.f, 0.f, 0.f, 0.f};

  const unsigned short* Bg = Wtf + (size_t)lane * 8;  // + ((ntile*16+ks)*512)
  const int sw = l15 & 7;  // A swizzle key (m&7 == l15&7)

#pragma unroll
  for (int c = 0; c < 4; ++c) {  // 4 k-chunks of 128
    f32x4 r0, r1, r2, r3;
    if (c < 3) {
      // issue-early: next chunk's HBM loads in flight under the MFMAs
      const f32x4* s4 = (const f32x4*)(src + (c + 1) * 128);
      r0 = s4[0];
      r1 = s4[1];
      r2 = s4[2];
      r3 = s4[3];
      asm volatile("" : "+v"(r0), "+v"(r1), "+v"(r2), "+v"(r3));
    }

    const unsigned short* Ac = &Ab[c & 1][0];
#pragma unroll
    for (int kl = 0; kl < 4; ++kl) {  // 4 k-steps of 32 within chunk
      const int ks = c * 4 + kl;
      bf16x8 bfr[4], af[4];
#pragma unroll
      for (int nt = 0; nt < 4; ++nt)
        bfr[nt] = *(const bf16x8*)(Bg + (size_t)((w * 4 + nt) * 16 + ks) * 512);
#pragma unroll
      for (int mt = 0; mt < 4; ++mt)
        af[mt] = *(const bf16x8*)&Ac[(mt * 16 + l15) * 128 + (((kl * 4 + quad) ^ sw) * 8)];
#pragma unroll
      for (int mt = 0; mt < 4; ++mt)
#pragma unroll
        for (int nt = 0; nt < 4; ++nt)
          acc[mt][nt] = __builtin_amdgcn_mfma_f32_16x16x32_bf16(af[mt], bfr[nt],
                                                                acc[mt][nt], 0, 0, 0);
    }

    if (c < 3) {
      // write-late: convert + ds_write into the other buffer
      const unsigned int p0 = cvt_pk_bf16(r0[0], r0[1]);
      const unsigned int p1 = cvt_pk_bf16(r0[2], r0[3]);
      const unsigned int p2 = cvt_pk_bf16(r1[0], r1[1]);
      const unsigned int p3 = cvt_pk_bf16(r1[2], r1[3]);
      const unsigned int p4 = cvt_pk_bf16(r2[0], r2[1]);
      const unsigned int p5 = cvt_pk_bf16(r2[2], r2[3]);
      const unsigned int p6 = cvt_pk_bf16(r3[0], r3[1]);
      const unsigned int p7 = cvt_pk_bf16(r3[2], r3[3]);
      *(uint4*)&Ab[(c + 1) & 1][wo0] = make_uint4(p0, p1, p2, p3);
      *(uint4*)&Ab[(c + 1) & 1][wo1] = make_uint4(p4, p5, p6, p7);
    }
    __syncthreads();
  }

  // ---- epilogue: part[m] += tanh(acc + Q[b,n]) * V1[n], reduce over n
  // C/D layout: col(n) = lane&15, row(m within tile) = quad*4 + r
  float part[4][4];
#pragma unroll
  for (int mt = 0; mt < 4; ++mt)
#pragma unroll
    for (int r = 0; r < 4; ++r) part[mt][r] = 0.f;

#pragma unroll
  for (int nt = 0; nt < 4; ++nt) {
    const int n = w * 64 + nt * 16 + l15;
    const float qv = Q[b * 512 + n];
    const float v1 = V1[n];
#pragma unroll
    for (int mt = 0; mt < 4; ++mt)
#pragma unroll
      for (int r = 0; r < 4; ++r) {
        const float x = acc[mt][nt][r] + qv;
        const float e = fast_exp2(x * 2.8853900817779268f);  // e^{2x}
        const float th = 1.0f - 2.0f * fast_rcp(e + 1.0f);   // tanh(x)
        part[mt][r] += th * v1;
      }
  }
#pragma unroll
  for (int mt = 0; mt < 4; ++mt)
#pragma unroll
    for (int r = 0; r < 4; ++r) {
      float v = part[mt][r];
      v += __shfl_xor(v, 1);
      v += __shfl_xor(v, 2);
      v += __shfl_xor(v, 4);
      v += __shfl_xor(v, 8);
      if (l15 == 0) atomicAdd(&sAcc[mt * 16 + quad * 4 + r], v);
    }
  __syncthreads();

  // ---- local softmax partials (wave 0: lanes 0..63 own the 64 rows)
  const float L2E = 1.4426950408889634f;
  if (t < 64) {
    const float v = sAcc[t];
    float m = v;
#pragma unroll
    for (int o = 1; o < 64; o <<= 1) m = fmaxf(m, __shfl_xor(m, o));
    const float wv = fast_exp2((v - m) * L2E);
    float dsum = wv;
#pragma unroll
    for (int o = 1; o < 64; o <<= 1) dsum += __shfl_xor(dsum, o);
    wLDS[t] = wv;
    if (t == 0) {
      Pstat[2 * blk] = m;
      Pstat[2 * blk + 1] = dsum;
    }
  }
  __syncthreads();

  // ---- partial context: thread t owns column u=t over the block's 64 rows.
  // fp32 re-read from global (rows just streamed -> mostly L2-hit).
  const float* vrow = values + (size_t)m0 * 512 + t;
  float cacc = 0.f;
#pragma unroll 8
  for (int r = 0; r < 64; ++r) cacc += wLDS[r] * vrow[(size_t)r * 512];
  Pctx[(size_t)blk * 512 + t] = cacc;
}

// ---------------- k3: combine partials ------------------------------------
// grid 64 (one per b) x 512 thr. 32 partials per b: global max M, denom
// D = sum d_i*exp(m_i-M); out[b,d] = sum_i ctx_i[d]*exp(m_i-M) / D. 4MB read.
__global__ __launch_bounds__(512) void comb_k(const float* __restrict__ Pstat,
                                              const float* __restrict__ Pctx,
                                              float* __restrict__ out) {
  __shared__ float aL[32];
  __shared__ float Dsh;
  const int b = blockIdx.x, t = threadIdx.x;
  const float L2E = 1.4426950408889634f;
  if (t < 32) {
    const float2 st = ((const float2*)Pstat)[b * 32 + t];
    float m = st.x;
#pragma unroll
    for (int o = 1; o < 32; o <<= 1) m = fmaxf(m, __shfl_xor(m, o));
    const float a = fast_exp2((st.x - m) * L2E);
    float D = a * st.y;
#pragma unroll
    for (int o = 1; o < 32; o <<= 1) D += __shfl_xor(D, o);
    aL[t] = a;
    if (t == 0) Dsh = D;
  }
  __syncthreads();
  const float* pc = Pctx + (size_t)b * 32 * 512 + t;
  float acc = 0.f;
#pragma unroll
  for (int i = 0; i < 32; ++i) acc += aL[i] * pc[(size_t)i * 512];
  out[b * 512 + t] = acc / Dsh;
}

extern "C" void kernel_launch(void* const* d_in, const int* in_sizes, int n_in,
                              void* d_out, int out_size, void* d_ws, size_t ws_size,
                              hipStream_t stream) {
  const float* query = (const float*)d_in[0];   // (64, 512)
  const float* values = (const float*)d_in[1];  // (64, 2048, 512)
  const float* W1 = (const float*)d_in[2];      // (512, 512)
  const float* W2 = (const float*)d_in[3];      // (512, 512)
  const float* V1 = (const float*)d_in[4];      // (512, 1)
  float* out = (float*)d_out;                   // (64, 512)

  char* ws = (char*)d_ws;
  float* Qp = (float*)ws;                                // 131072 B
  unsigned short* Wtp = (unsigned short*)(ws + 131072);  // 524288 B
  float* Pstat = (float*)(ws + 131072 + 524288);         // 16384 B (2048 x 2)
  float* Pctx = (float*)(ws + 131072 + 524288 + 16384);  // 4 MB (2048 x 512)

  prep_k<<<256, 256, 0, stream>>>(query, W1, W2, Qp, Wtp);
  scorectx_k<<<2048, 512, 0, stream>>>(values, Wtp, Qp, V1, Pstat, Pctx);
  comb_k<<<64, 512, 0, stream>>>(Pstat, Pctx, out);
}

// Round 8
// 475.739 us; speedup vs baseline: 1.0356x; 1.0356x over previous
//
#include <hip/hip_runtime.h>
#include <hip/hip_bf16.h>

// AdditiveAttention on MI355X (gfx950)
// B=64, S=2048, D=512, U=512. All inputs fp32; output fp32 (B,D).
//
// R10: accumulator slimming. R5-R9 established: acc[4][4]=64 AGPR/lane forces
// either spills (2 blk/CU, 177us) or exposed staging (1 blk/CU, 195us).
// Now 16 waves x 1024 thr per 64x512 tile: wave owns 64rows x 32cols ->
// acc[4][2]=32 AGPR. launch_bounds(1024,4): <=128 regs, 4 waves/SIMD (same
// TLP as R8-best) with ~90 free VGPRs -> explicit 1-kstep-ahead B(global)+
// A(LDS) prefetch, BK=128 double-buffered A-stage (2x16KB) issue-early/
// write-late. No spills + pipeline + full TLP simultaneously (first time).

typedef __attribute__((ext_vector_type(8))) short bf16x8;
typedef __attribute__((ext_vector_type(4))) float f32x4;

#if __has_builtin(__builtin_amdgcn_exp2f)
__device__ __forceinline__ float fast_exp2(float x) { return __builtin_amdgcn_exp2f(x); }
#else
__device__ __forceinline__ float fast_exp2(float x) { return exp2f(x); }
#endif
#if __has_builtin(__builtin_amdgcn_rcpf)
__device__ __forceinline__ float fast_rcp(float x) { return __builtin_amdgcn_rcpf(x); }
#else
__device__ __forceinline__ float fast_rcp(float x) { return 1.0f / x; }
#endif

__device__ __forceinline__ unsigned short f2bf(float f) {
  unsigned int u = __float_as_uint(f);
  u += 0x7fffu + ((u >> 16) & 1u);
  return (unsigned short)(u >> 16);
}

// pack two fp32 -> one dword of 2 bf16 (lo = a, hi = b), RNE via HIP intrinsics
__device__ __forceinline__ unsigned int cvt_pk_bf16(float a, float b) {
  const __hip_bfloat16 lo = __float2bfloat16(a);
  const __hip_bfloat16 hi = __float2bfloat16(b);
  const unsigned short ul = *reinterpret_cast<const unsigned short*>(&lo);
  const unsigned short uh = *reinterpret_cast<const unsigned short*>(&hi);
  return (unsigned int)ul | ((unsigned int)uh << 16);
}

// ---------------- k1: fused prep = qk (blocks 0..127) + wt_k (128..255) -----
// qk: Q = query @ W1, 64x2 sub-blocks x 256 thr.
// wt: Wtf fragment-ordered bf16(W2^T):
// Wtf[((ntile*16+ks)*64 + quad*16 + l15)*8 + j] = bf16(W2[ks*32+quad*8+j][ntile*16+l15])
__global__ __launch_bounds__(256) void prep_k(
    const float* __restrict__ query, const float* __restrict__ W1,
    const float* __restrict__ W2, float* __restrict__ Q,
    unsigned short* __restrict__ Wtf) {
  __shared__ float qrow[512];
  const int t = threadIdx.x;
  if (blockIdx.x < 128) {
    const int b = blockIdx.x >> 1, half = blockIdx.x & 1;
    qrow[t] = query[b * 512 + t];
    qrow[t + 256] = query[b * 512 + t + 256];
    __syncthreads();
    const int u = half * 256 + t;
    float acc = 0.f;
#pragma unroll 8
    for (int k = 0; k < 512; ++k) acc += qrow[k] * W1[(size_t)k * 512 + u];
    Q[b * 512 + u] = acc;
  } else {
    const int gid = (blockIdx.x - 128) * 256 + t;  // 0..32767
    const int lane = gid & 63;
    const int g = gid >> 6;  // ntile*16 + ks
    const int ks = g & 15, ntile = g >> 4;
    const int l15 = lane & 15, quad = lane >> 4;
    const int n = ntile * 16 + l15;
    const int k0 = ks * 32 + quad * 8;
    unsigned int p[4];
#pragma unroll
    for (int jj = 0; jj < 4; ++jj) {
      const float a = W2[(size_t)(k0 + 2 * jj) * 512 + n];
      const float b = W2[(size_t)(k0 + 2 * jj + 1) * 512 + n];
      p[jj] = (unsigned int)f2bf(a) | ((unsigned int)f2bf(b) << 16);
    }
    *(uint4*)&Wtf[(size_t)gid * 8] = make_uint4(p[0], p[1], p[2], p[3]);
  }
}

// ---------------- k2: fused scores + split-softmax partial context ----------
// Block: 64 rows x full U=512, K=512. 16 waves; wave w owns ntiles 2w, 2w+1
// (cols w*32..w*32+31), acc[4][2]=32 AGPR/lane.
// A staged per 128-k chunk as bf16 (1 unit of 8 floats per thread), double-
// buffered 2x16KB, XOR-swizzled; chunk c+1 loads issued before chunk c MFMAs.
// B fragments from fragment-ordered Wtf (L2-res), prefetched 1 kstep ahead.
// Epilogue: tanh+V1 reduce -> sAcc -> local softmax -> partial ctx (1024 thr,
// rows split 32/32, LDS combine).
__global__ __launch_bounds__(1024, 4) void scorectx_k(
    const float* __restrict__ values, const unsigned short* __restrict__ Wtf,
    const float* __restrict__ Q, const float* __restrict__ V1,
    float* __restrict__ Pstat, float* __restrict__ Pctx) {
  __shared__ __align__(16) unsigned short Ab[2][64 * 128];  // 2 x 16KB
  __shared__ float sAcc[64];
  __shared__ float wLDS[64];
  __shared__ float pLDS[1024];

  const int t = threadIdx.x;
  const int lane = t & 63;
  const int w = t >> 6;        // wave 0..15
  const int quad = lane >> 4;  // 0..3
  const int l15 = lane & 15;
  const int blk = blockIdx.x;
  const int m0 = blk * 64;
  const int b = m0 >> 11;  // /2048

  if (t < 64) sAcc[t] = 0.0f;

  // Staging geometry: thread t owns row sm = t>>4, 8 floats at unit sp = t&15
  // of the current 128-k chunk. One 16B LDS write, XOR-swizzled by sm&7.
  const int sm = t >> 4;  // 0..63
  const int sp = t & 15;  // 0..15
  const int sk = sm & 7;
  const float* src = values + (size_t)(m0 + sm) * 512 + sp * 8;
  const int wo = sm * 128 + ((sp ^ sk) * 8);

  // ---- prologue: stage chunk 0 into buf 0
  {
    const f32x4 x = *(const f32x4*)src;
    const f32x4 y = *(const f32x4*)(src + 4);
    *(uint4*)&Ab[0][wo] = make_uint4(cvt_pk_bf16(x[0], x[1]), cvt_pk_bf16(x[2], x[3]),
                                     cvt_pk_bf16(y[0], y[1]), cvt_pk_bf16(y[2], y[3]));
  }
  __syncthreads();

  f32x4 acc[4][2];
#pragma unroll
  for (int mt = 0; mt < 4; ++mt) {
    acc[mt][0] = (f32x4){0.f, 0.f, 0.f, 0.f};
    acc[mt][1] = (f32x4){0.f, 0.f, 0.f, 0.f};
  }

  const int sw = l15 & 7;  // A swizzle key (m&7 == l15&7)
  // B fragment base for this wave's two ntiles (2w, 2w+1)
  const unsigned short* B0 = Wtf + (size_t)(w * 2) * 16 * 512 + (size_t)lane * 8;
  const unsigned short* B1 = B0 + (size_t)16 * 512;

  // prime B prefetch (ks = 0)
  bf16x8 bc0 = *(const bf16x8*)B0;
  bf16x8 bc1 = *(const bf16x8*)B1;

#pragma unroll
  for (int c = 0; c < 4; ++c) {  // 4 k-chunks of 128
    f32x4 sx, sy;
    if (c < 3) {
      // issue-early: next chunk's HBM loads in flight under this chunk's MFMAs
      sx = *(const f32x4*)(src + (c + 1) * 128);
      sy = *(const f32x4*)(src + (c + 1) * 128 + 4);
    }

    const unsigned short* Ac = &Ab[c & 1][0];
    // A frags for kl=0
    bf16x8 af[4], an[4];
#pragma unroll
    for (int mt = 0; mt < 4; ++mt)
      af[mt] = *(const bf16x8*)&Ac[(mt * 16 + l15) * 128 + ((quad ^ sw) * 8)];

#pragma unroll
    for (int kl = 0; kl < 4; ++kl) {  // 4 k-steps of 32 within chunk
      const int ks = c * 4 + kl;
      bf16x8 bn0, bn1;
      if (ks < 15) {  // B prefetch next kstep (global, buffer-independent)
        bn0 = *(const bf16x8*)(B0 + (size_t)(ks + 1) * 512);
        bn1 = *(const bf16x8*)(B1 + (size_t)(ks + 1) * 512);
      }
      if (kl < 3) {  // A prefetch next kstep (same LDS buffer)
#pragma unroll
        for (int mt = 0; mt < 4; ++mt)
          an[mt] = *(const bf16x8*)&Ac[(mt * 16 + l15) * 128 +
                                       ((((kl + 1) * 4 + quad) ^ sw) * 8)];
      }
#pragma unroll
      for (int mt = 0; mt < 4; ++mt) {
        acc[mt][0] = __builtin_amdgcn_mfma_f32_16x16x32_bf16(af[mt], bc0, acc[mt][0], 0, 0, 0);
        acc[mt][1] = __builtin_amdgcn_mfma_f32_16x16x32_bf16(af[mt], bc1, acc[mt][1], 0, 0, 0);
      }
      bc0 = bn0;
      bc1 = bn1;
      if (kl < 3) {
#pragma unroll
        for (int mt = 0; mt < 4; ++mt) af[mt] = an[mt];
      }
    }

    if (c < 3) {
      // write-late: convert + ds_write into the other buffer
      *(uint4*)&Ab[(c + 1) & 1][wo] =
          make_uint4(cvt_pk_bf16(sx[0], sx[1]), cvt_pk_bf16(sx[2], sx[3]),
                     cvt_pk_bf16(sy[0], sy[1]), cvt_pk_bf16(sy[2], sy[3]));
    }
    __syncthreads();
  }

  // ---- epilogue: part[m] += tanh(acc + Q[b,n]) * V1[n], reduce over n
  // C/D layout: col(n) = lane&15, row(m within tile) = quad*4 + r
  float part[4][4];
#pragma unroll
  for (int mt = 0; mt < 4; ++mt)
#pragma unroll
    for (int r = 0; r < 4; ++r) part[mt][r] = 0.f;

#pragma unroll
  for (int nt = 0; nt < 2; ++nt) {
    const int n = (w * 2 + nt) * 16 + l15;
    const float qv = Q[b * 512 + n];
    const float v1 = V1[n];
#pragma unroll
    for (int mt = 0; mt < 4; ++mt)
#pragma unroll
      for (int r = 0; r < 4; ++r) {
        const float x = acc[mt][nt][r] + qv;
        const float e = fast_exp2(x * 2.8853900817779268f);  // e^{2x}
        const float th = 1.0f - 2.0f * fast_rcp(e + 1.0f);   // tanh(x)
        part[mt][r] += th * v1;
      }
  }
#pragma unroll
  for (int mt = 0; mt < 4; ++mt)
#pragma unroll
    for (int r = 0; r < 4; ++r) {
      float v = part[mt][r];
      v += __shfl_xor(v, 1);
      v += __shfl_xor(v, 2);
      v += __shfl_xor(v, 4);
      v += __shfl_xor(v, 8);
      if (l15 == 0) atomicAdd(&sAcc[mt * 16 + quad * 4 + r], v);
    }
  __syncthreads();

  // ---- local softmax partials (wave 0: lanes 0..63 own the 64 rows)
  const float L2E = 1.4426950408889634f;
  if (t < 64) {
    const float v = sAcc[t];
    float m = v;
#pragma unroll
    for (int o = 1; o < 64; o <<= 1) m = fmaxf(m, __shfl_xor(m, o));
    const float wv = fast_exp2((v - m) * L2E);
    float dsum = wv;
#pragma unroll
    for (int o = 1; o < 64; o <<= 1) dsum += __shfl_xor(dsum, o);
    wLDS[t] = wv;
    if (t == 0) {
      Pstat[2 * blk] = m;
      Pstat[2 * blk + 1] = dsum;
    }
  }
  __syncthreads();

  // ---- partial context: thread t owns column t&511, rows (t>>9)*32..+32.
  // fp32 re-read from global (rows just streamed -> mostly L2-hit).
  {
    const int rh = t >> 9;       // 0 or 1
    const int col = t & 511;
    const float* vrow = values + (size_t)(m0 + rh * 32) * 512 + col;
    float cacc = 0.f;
#pragma unroll 8
    for (int r = 0; r < 32; ++r) cacc += wLDS[rh * 32 + r] * vrow[(size_t)r * 512];
    pLDS[t] = cacc;
  }
  __syncthreads();
  if (t < 512) Pctx[(size_t)blk * 512 + t] = pLDS[t] + pLDS[t + 512];
}

// ---------------- k3: combine partials ------------------------------------
// grid 64 (one per b) x 512 thr. 32 partials per b: global max M, denom
// D = sum d_i*exp(m_i-M); out[b,d] = sum_i ctx_i[d]*exp(m_i-M) / D. 4MB read.
__global__ __launch_bounds__(512) void comb_k(const float* __restrict__ Pstat,
                                              const float* __restrict__ Pctx,
                                              float* __restrict__ out) {
  __shared__ float aL[32];
  __shared__ float Dsh;
  const int b = blockIdx.x, t = threadIdx.x;
  const float L2E = 1.4426950408889634f;
  if (t < 32) {
    const float2 st = ((const float2*)Pstat)[b * 32 + t];
    float m = st.x;
#pragma unroll
    for (int o = 1; o < 32; o <<= 1) m = fmaxf(m, __shfl_xor(m, o));
    const float a = fast_exp2((st.x - m) * L2E);
    float D = a * st.y;
#pragma unroll
    for (int o = 1; o < 32; o <<= 1) D += __shfl_xor(D, o);
    aL[t] = a;
    if (t == 0) Dsh = D;
  }
  __syncthreads();
  const float* pc = Pctx + (size_t)b * 32 * 512 + t;
  float acc = 0.f;
#pragma unroll
  for (int i = 0; i < 32; ++i) acc += aL[i] * pc[(size_t)i * 512];
  out[b * 512 + t] = acc / Dsh;
}

extern "C" void kernel_launch(void* const* d_in, const int* in_sizes, int n_in,
                              void* d_out, int out_size, void* d_ws, size_t ws_size,
                              hipStream_t stream) {
  const float* query = (const float*)d_in[0];   // (64, 512)
  const float* values = (const float*)d_in[1];  // (64, 2048, 512)
  const float* W1 = (const float*)d_in[2];      // (512, 512)
  const float* W2 = (const float*)d_in[3];      // (512, 512)
  const float* V1 = (const float*)d_in[4];      // (512, 1)
  float* out = (float*)d_out;                   // (64, 512)

  char* ws = (char*)d_ws;
  float* Qp = (float*)ws;                                // 131072 B
  unsigned short* Wtp = (unsigned short*)(ws + 131072);  // 524288 B
  float* Pstat = (float*)(ws + 131072 + 524288);         // 16384 B (2048 x 2)
  float* Pctx = (float*)(ws + 131072 + 524288 + 16384);  // 4 MB (2048 x 512)

  prep_k<<<256, 256, 0, stream>>>(query, W1, W2, Qp, Wtp);
  scorectx_k<<<2048, 1024, 0, stream>>>(values, Wtp, Qp, V1, Pstat, Pctx);
  comb_k<<<64, 512, 0, stream>>>(Pstat, Pctx, out);
}